// Round 1
// baseline (658.599 us; speedup 1.0000x reference)
//
#include <hip/hip_runtime.h>

#define BB 4
#define CC 256
#define HH 48
#define WW 48
#define HWHW 2304
#define KKH 7
#define KKW 7
#define PPAD 3
#define KK 49
#define RELN 128

// ws layout (floats): q | k | v | attn
#define QSZ (BB*CC*HWHW)        // 2359296 floats per tensor
#define ATTNOFF (3*QSZ)          // attn: [B][H][W][49]

// ---------------- Projection GEMM ----------------
// D[768][9216] = Wcat[768][256] * X[256][9216]
// tile M=128 (blockIdx.y), N=128 (blockIdx.x), K-step 32
__global__ __launch_bounds__(256) void proj_kernel(
    const float* __restrict__ x,
    const float* __restrict__ wq,
    const float* __restrict__ wk,
    const float* __restrict__ wvp,
    float* __restrict__ ws)
{
    __shared__ float Wt[32][132];  // transposed W tile [kk][m], padded stride
    __shared__ float Xs[32][128];

    const int m0 = blockIdx.y * 128;
    const int n0 = blockIdx.x * 128;
    const int b  = n0 / HWHW;        // N-tile never straddles batch (2304%128==0)
    const int hw0 = n0 % HWHW;

    const float* wsrc = (m0 < 256) ? wq : (m0 < 512) ? wk : wvp;
    const int mo = m0 & 255;

    const int tid = threadIdx.x;
    const int tn = tid & 15;
    const int tm = tid >> 4;

    float acc[2][2][4][4];
    #pragma unroll
    for (int p=0;p<2;p++)
      #pragma unroll
      for (int q=0;q<2;q++)
        #pragma unroll
        for (int i=0;i<4;i++)
          #pragma unroll
          for (int j=0;j<4;j++) acc[p][q][i][j]=0.f;

    const int wr = tid >> 1;    // W row 0..127
    const int wh = tid & 1;
    const int kkx = tid >> 3;   // X k-row 0..31
    const int cgx = tid & 7;

    for (int k0 = 0; k0 < 256; k0 += 32) {
        #pragma unroll
        for (int q4 = 0; q4 < 4; ++q4) {
            int koff = (wh*4 + q4) * 4;
            const float4 w4 = *(const float4*)(wsrc + (mo + wr)*256 + k0 + koff);
            Wt[koff+0][wr] = w4.x;
            Wt[koff+1][wr] = w4.y;
            Wt[koff+2][wr] = w4.z;
            Wt[koff+3][wr] = w4.w;
        }
        const float* xrow = x + (size_t)b*CC*HWHW + (size_t)(k0+kkx)*HWHW + hw0;
        #pragma unroll
        for (int j4 = 0; j4 < 4; ++j4) {
            int col = cgx*16 + j4*4;
            *(float4*)&Xs[kkx][col] = *(const float4*)(xrow + col);
        }
        __syncthreads();
        #pragma unroll
        for (int kk = 0; kk < 32; ++kk) {
            float4 a0 = *(const float4*)&Wt[kk][tm*4];
            float4 a1 = *(const float4*)&Wt[kk][64 + tm*4];
            float4 b0 = *(const float4*)&Xs[kk][tn*4];
            float4 b1 = *(const float4*)&Xs[kk][64 + tn*4];
            float av0[4] = {a0.x,a0.y,a0.z,a0.w};
            float av1[4] = {a1.x,a1.y,a1.z,a1.w};
            float bv0[4] = {b0.x,b0.y,b0.z,b0.w};
            float bv1[4] = {b1.x,b1.y,b1.z,b1.w};
            #pragma unroll
            for (int i=0;i<4;i++) {
                #pragma unroll
                for (int j=0;j<4;j++) {
                    acc[0][0][i][j] += av0[i]*bv0[j];
                    acc[0][1][i][j] += av0[i]*bv1[j];
                    acc[1][0][i][j] += av1[i]*bv0[j];
                    acc[1][1][i][j] += av1[i]*bv1[j];
                }
            }
        }
        __syncthreads();
    }
    #pragma unroll
    for (int p=0;p<2;p++) {
        #pragma unroll
        for (int i=0;i<4;i++) {
            int m = m0 + p*64 + tm*4 + i;
            int proj = m >> 8;
            int ch = m & 255;
            float* dst = ws + (size_t)proj*QSZ + (size_t)b*CC*HWHW + (size_t)ch*HWHW + hw0;
            #pragma unroll
            for (int q=0;q<2;q++) {
                int col = q*64 + tn*4;
                float4 o;
                o.x = acc[p][q][i][0]; o.y = acc[p][q][i][1];
                o.z = acc[p][q][i][2]; o.w = acc[p][q][i][3];
                *(float4*)(dst + col) = o;
            }
        }
    }
}

// ---------------- Scores + softmax ----------------
// block per (b,h); 4 waves split channels (64 each); LDS cross-wave reduce.
__global__ __launch_bounds__(256) void attn_scores_kernel(
    const float* __restrict__ relx,
    const float* __restrict__ rely,
    float* __restrict__ ws)
{
    const float* qbuf = ws;
    const float* kbuf = ws + QSZ;
    float* attn = ws + ATTNOFF;

    __shared__ float ks[4][4][7][56];   // [wave][ch-in-group][dk][col(-3..50)]
    __shared__ float red[4][48][65];    // partial scores+qx+qy, padded stride

    const int bh = blockIdx.x;
    const int b = bh / HH;
    const int h = bh % HH;
    const int tid = threadIdx.x;
    const int wvv = tid >> 6;
    const int lane = tid & 63;
    const int w = lane;
    const bool act = (w < WW);

    float s[KK];
    #pragma unroll
    for (int i=0;i<KK;i++) s[i]=0.f;
    float qxa[7] = {0,0,0,0,0,0,0};
    float qya[7] = {0,0,0,0,0,0,0};

    for (int g = 0; g < 16; ++g) {
        // stage 4 channels x 7 rows x 54 cols of k (zero for OOB)
        for (int t = 0; t < 24; ++t) {
            int fi = lane + t*64;
            if (fi < 1512) {
                int ci = fi / 378;
                int rem = fi - ci*378;
                int rw = rem / 54;
                int cl = rem - rw*54;
                int ch = wvv*64 + g*4 + ci;
                int gr = h + rw - 3;
                int gc = cl - 3;
                float v = 0.f;
                if (gr >= 0 && gr < HH && gc >= 0 && gc < WW)
                    v = kbuf[((size_t)b*CC + ch)*HWHW + gr*WW + gc];
                ks[wvv][ci][rw][cl] = v;
            }
        }
        __syncthreads();
        if (act) {
            #pragma unroll
            for (int ci = 0; ci < 4; ++ci) {
                int ch = wvv*64 + g*4 + ci;
                float qv = qbuf[((size_t)b*CC + ch)*HWHW + h*WW + w];
                if (ch < RELN) {
                    const float* rel = relx + ch*7;
                    #pragma unroll
                    for (int l = 0; l < 7; ++l) qxa[l] += qv * rel[l];
                } else {
                    const float* rel = rely + (ch-RELN)*7;
                    #pragma unroll
                    for (int l = 0; l < 7; ++l) qya[l] += qv * rel[l];
                }
                #pragma unroll
                for (int dk = 0; dk < 7; ++dk) {
                    #pragma unroll
                    for (int dl = 0; dl < 7; ++dl) {
                        s[dk*7+dl] += qv * ks[wvv][ci][dk][w + dl];
                    }
                }
            }
        }
        __syncthreads();
    }

    if (act) {
        #pragma unroll
        for (int i=0;i<KK;i++) red[wvv][w][i] = s[i];
        #pragma unroll
        for (int l=0;l<7;l++) { red[wvv][w][49+l] = qxa[l]; red[wvv][w][56+l] = qya[l]; }
    }
    __syncthreads();
    if (wvv == 0 && act) {
        float tot[KK]; float qx_t[7]; float qy_t[7];
        #pragma unroll
        for (int i=0;i<KK;i++)
            tot[i] = red[0][w][i]+red[1][w][i]+red[2][w][i]+red[3][w][i];
        #pragma unroll
        for (int l=0;l<7;l++) {
            qx_t[l] = red[0][w][49+l]+red[1][w][49+l]+red[2][w][49+l]+red[3][w][49+l];
            qy_t[l] = red[0][w][56+l]+red[1][w][56+l]+red[2][w][56+l]+red[3][w][56+l];
        }
        float mx = -1e30f;
        #pragma unroll
        for (int dk=0;dk<7;dk++) {
            #pragma unroll
            for (int dl=0;dl<7;dl++) {
                tot[dk*7+dl] += qy_t[dk] + qx_t[dl];
                mx = fmaxf(mx, tot[dk*7+dl]);
            }
        }
        float sum = 0.f;
        #pragma unroll
        for (int i=0;i<KK;i++) { float e = __expf(tot[i]-mx); tot[i]=e; sum += e; }
        float inv = 1.f/sum;
        float* adst = attn + ((size_t)(b*HH + h)*WW + w)*KK;
        #pragma unroll
        for (int i=0;i<KK;i++) adst[i] = tot[i]*inv;
    }
}

// ---------------- PV + bias ----------------
__global__ __launch_bounds__(256) void pv_kernel(
    const float* __restrict__ bias,
    const float* __restrict__ ws,
    float* __restrict__ out)
{
    const float* vbuf = ws + 2*QSZ;
    const float* attn = ws + ATTNOFF;
    int o = blockIdx.x*256 + threadIdx.x;
    int w = o % WW;
    int h = (o / WW) % HH;
    int c = (o / HWHW) % CC;
    int b = o / (HWHW*CC);
    const float* a = attn + ((size_t)(b*HH+h)*WW + w)*KK;
    const float* vb = vbuf + ((size_t)b*CC + c)*HWHW;
    float acc = bias[c];
    #pragma unroll
    for (int dk=0;dk<7;dk++) {
        int gr = h + dk - 3;
        if (gr < 0 || gr >= HH) continue;
        #pragma unroll
        for (int dl=0;dl<7;dl++) {
            int gc = w + dl - 3;
            if (gc < 0 || gc >= WW) continue;
            acc += a[dk*7+dl] * vb[gr*WW + gc];
        }
    }
    out[o] = acc;
}

extern "C" void kernel_launch(void* const* d_in, const int* in_sizes, int n_in,
                              void* d_out, int out_size, void* d_ws, size_t ws_size,
                              hipStream_t stream) {
    const float* x    = (const float*)d_in[0];
    const float* wq   = (const float*)d_in[1];
    const float* wk   = (const float*)d_in[2];
    const float* wv   = (const float*)d_in[3];
    const float* bias = (const float*)d_in[4];
    const float* relx = (const float*)d_in[5];
    const float* rely = (const float*)d_in[6];
    float* ws  = (float*)d_ws;
    float* out = (float*)d_out;

    proj_kernel<<<dim3(72, 6), dim3(256), 0, stream>>>(x, wq, wk, wv, ws);
    attn_scores_kernel<<<dim3(192), dim3(256), 0, stream>>>(relx, rely, ws);
    pv_kernel<<<dim3(9216), dim3(256), 0, stream>>>(bias, ws, out);
}

// Round 2
// 309.580 us; speedup vs baseline: 2.1274x; 2.1274x over previous
//
#include <hip/hip_runtime.h>

#define BB 4
#define CC 256
#define HH 48
#define WW 48
#define HWHW 2304
#define KKH 7
#define KKW 7
#define PPAD 3
#define KK 49
#define RELN 128

// ws layout (floats): q | k | v | attn
#define QSZ (BB*CC*HWHW)        // 2359296 floats per tensor
#define ATTNOFF (3*QSZ)          // attn: [B][H][49][W]  (transposed: tap-major, w minor)

// ---------------- Projection GEMM ----------------
// D[768][9216] = Wcat[768][256] * X[256][9216]
// tile M=128 (blockIdx.y), N=128 (blockIdx.x), K-step 32
__global__ __launch_bounds__(256) void proj_kernel(
    const float* __restrict__ x,
    const float* __restrict__ wq,
    const float* __restrict__ wk,
    const float* __restrict__ wvp,
    float* __restrict__ ws)
{
    __shared__ float Wt[32][132];  // transposed W tile [kk][m], padded stride
    __shared__ float Xs[32][128];

    const int m0 = blockIdx.y * 128;
    const int n0 = blockIdx.x * 128;
    const int b  = n0 / HWHW;        // N-tile never straddles batch (2304%128==0)
    const int hw0 = n0 % HWHW;

    const float* wsrc = (m0 < 256) ? wq : (m0 < 512) ? wk : wvp;
    const int mo = m0 & 255;

    const int tid = threadIdx.x;
    const int tn = tid & 15;
    const int tm = tid >> 4;

    float acc[2][2][4][4];
    #pragma unroll
    for (int p=0;p<2;p++)
      #pragma unroll
      for (int q=0;q<2;q++)
        #pragma unroll
        for (int i=0;i<4;i++)
          #pragma unroll
          for (int j=0;j<4;j++) acc[p][q][i][j]=0.f;

    const int wr = tid >> 1;    // W row 0..127
    const int wh = tid & 1;
    const int kkx = tid >> 3;   // X k-row 0..31
    const int cgx = tid & 7;

    for (int k0 = 0; k0 < 256; k0 += 32) {
        #pragma unroll
        for (int q4 = 0; q4 < 4; ++q4) {
            int koff = (wh*4 + q4) * 4;
            const float4 w4 = *(const float4*)(wsrc + (mo + wr)*256 + k0 + koff);
            Wt[koff+0][wr] = w4.x;
            Wt[koff+1][wr] = w4.y;
            Wt[koff+2][wr] = w4.z;
            Wt[koff+3][wr] = w4.w;
        }
        const float* xrow = x + (size_t)b*CC*HWHW + (size_t)(k0+kkx)*HWHW + hw0;
        #pragma unroll
        for (int j4 = 0; j4 < 4; ++j4) {
            int col = cgx*16 + j4*4;
            *(float4*)&Xs[kkx][col] = *(const float4*)(xrow + col);
        }
        __syncthreads();
        #pragma unroll
        for (int kk = 0; kk < 32; ++kk) {
            float4 a0 = *(const float4*)&Wt[kk][tm*4];
            float4 a1 = *(const float4*)&Wt[kk][64 + tm*4];
            float4 b0 = *(const float4*)&Xs[kk][tn*4];
            float4 b1 = *(const float4*)&Xs[kk][64 + tn*4];
            float av0[4] = {a0.x,a0.y,a0.z,a0.w};
            float av1[4] = {a1.x,a1.y,a1.z,a1.w};
            float bv0[4] = {b0.x,b0.y,b0.z,b0.w};
            float bv1[4] = {b1.x,b1.y,b1.z,b1.w};
            #pragma unroll
            for (int i=0;i<4;i++) {
                #pragma unroll
                for (int j=0;j<4;j++) {
                    acc[0][0][i][j] += av0[i]*bv0[j];
                    acc[0][1][i][j] += av0[i]*bv1[j];
                    acc[1][0][i][j] += av1[i]*bv0[j];
                    acc[1][1][i][j] += av1[i]*bv1[j];
                }
            }
        }
        __syncthreads();
    }
    #pragma unroll
    for (int p=0;p<2;p++) {
        #pragma unroll
        for (int i=0;i<4;i++) {
            int m = m0 + p*64 + tm*4 + i;
            int proj = m >> 8;
            int ch = m & 255;
            float* dst = ws + (size_t)proj*QSZ + (size_t)b*CC*HWHW + (size_t)ch*HWHW + hw0;
            #pragma unroll
            for (int q=0;q<2;q++) {
                int col = q*64 + tn*4;
                float4 o;
                o.x = acc[p][q][i][0]; o.y = acc[p][q][i][1];
                o.z = acc[p][q][i][2]; o.w = acc[p][q][i][3];
                *(float4*)(dst + col) = o;
            }
        }
    }
}

// ---------------- Scores + softmax ----------------
// block per (b,h); 4 waves split channels (64 each); LDS cross-wave reduce.
// Writes attn TRANSPOSED: [B][H][49][W] so pv_kernel reads are coalesced.
__global__ __launch_bounds__(256) void attn_scores_kernel(
    const float* __restrict__ relx,
    const float* __restrict__ rely,
    float* __restrict__ ws)
{
    const float* qbuf = ws;
    const float* kbuf = ws + QSZ;
    float* attn = ws + ATTNOFF;

    __shared__ float ks[4][4][7][56];   // [wave][ch-in-group][dk][col(-3..50)]
    __shared__ float red[4][48][65];    // partial scores+qx+qy, padded stride

    const int bh = blockIdx.x;
    const int b = bh / HH;
    const int h = bh % HH;
    const int tid = threadIdx.x;
    const int wvv = tid >> 6;
    const int lane = tid & 63;
    const int w = lane;
    const bool act = (w < WW);

    float s[KK];
    #pragma unroll
    for (int i=0;i<KK;i++) s[i]=0.f;
    float qxa[7] = {0,0,0,0,0,0,0};
    float qya[7] = {0,0,0,0,0,0,0};

    for (int g = 0; g < 16; ++g) {
        // stage 4 channels x 7 rows x 54 cols of k (zero for OOB)
        for (int t = 0; t < 24; ++t) {
            int fi = lane + t*64;
            if (fi < 1512) {
                int ci = fi / 378;
                int rem = fi - ci*378;
                int rw = rem / 54;
                int cl = rem - rw*54;
                int ch = wvv*64 + g*4 + ci;
                int gr = h + rw - 3;
                int gc = cl - 3;
                float v = 0.f;
                if (gr >= 0 && gr < HH && gc >= 0 && gc < WW)
                    v = kbuf[((size_t)b*CC + ch)*HWHW + gr*WW + gc];
                ks[wvv][ci][rw][cl] = v;
            }
        }
        __syncthreads();
        if (act) {
            #pragma unroll
            for (int ci = 0; ci < 4; ++ci) {
                int ch = wvv*64 + g*4 + ci;
                float qv = qbuf[((size_t)b*CC + ch)*HWHW + h*WW + w];
                if (ch < RELN) {
                    const float* rel = relx + ch*7;
                    #pragma unroll
                    for (int l = 0; l < 7; ++l) qxa[l] += qv * rel[l];
                } else {
                    const float* rel = rely + (ch-RELN)*7;
                    #pragma unroll
                    for (int l = 0; l < 7; ++l) qya[l] += qv * rel[l];
                }
                #pragma unroll
                for (int dk = 0; dk < 7; ++dk) {
                    #pragma unroll
                    for (int dl = 0; dl < 7; ++dl) {
                        s[dk*7+dl] += qv * ks[wvv][ci][dk][w + dl];
                    }
                }
            }
        }
        __syncthreads();
    }

    if (act) {
        #pragma unroll
        for (int i=0;i<KK;i++) red[wvv][w][i] = s[i];
        #pragma unroll
        for (int l=0;l<7;l++) { red[wvv][w][49+l] = qxa[l]; red[wvv][w][56+l] = qya[l]; }
    }
    __syncthreads();
    if (wvv == 0 && act) {
        float tot[KK]; float qx_t[7]; float qy_t[7];
        #pragma unroll
        for (int i=0;i<KK;i++)
            tot[i] = red[0][w][i]+red[1][w][i]+red[2][w][i]+red[3][w][i];
        #pragma unroll
        for (int l=0;l<7;l++) {
            qx_t[l] = red[0][w][49+l]+red[1][w][49+l]+red[2][w][49+l]+red[3][w][49+l];
            qy_t[l] = red[0][w][56+l]+red[1][w][56+l]+red[2][w][56+l]+red[3][w][56+l];
        }
        float mx = -1e30f;
        #pragma unroll
        for (int dk=0;dk<7;dk++) {
            #pragma unroll
            for (int dl=0;dl<7;dl++) {
                tot[dk*7+dl] += qy_t[dk] + qx_t[dl];
                mx = fmaxf(mx, tot[dk*7+dl]);
            }
        }
        float sum = 0.f;
        #pragma unroll
        for (int i=0;i<KK;i++) { float e = __expf(tot[i]-mx); tot[i]=e; sum += e; }
        float inv = 1.f/sum;
        // transposed write: attn[b][h][tap][w]
        float* adst = attn + ((size_t)(b*HH + h)*KK)*WW + w;
        #pragma unroll
        for (int i=0;i<KK;i++) adst[(size_t)i*WW] = tot[i]*inv;
    }
}

// ---------------- PV + bias ----------------
// attn now [B][H][49][W]: the 49 per-thread attn loads are coalesced across w lanes.
__global__ __launch_bounds__(256) void pv_kernel(
    const float* __restrict__ bias,
    const float* __restrict__ ws,
    float* __restrict__ out)
{
    const float* vbuf = ws + 2*QSZ;
    const float* attn = ws + ATTNOFF;
    int o = blockIdx.x*256 + threadIdx.x;
    int w = o % WW;
    int h = (o / WW) % HH;
    int c = (o / HWHW) % CC;
    int b = o / (HWHW*CC);
    const float* a = attn + ((size_t)(b*HH+h)*KK)*WW + w;   // + tap*WW
    const float* vb = vbuf + ((size_t)b*CC + c)*HWHW;
    float acc = bias[c];
    #pragma unroll
    for (int dk=0;dk<7;dk++) {
        int gr = h + dk - 3;
        if (gr < 0 || gr >= HH) continue;
        #pragma unroll
        for (int dl=0;dl<7;dl++) {
            int gc = w + dl - 3;
            if (gc < 0 || gc >= WW) continue;
            acc += a[(size_t)(dk*7+dl)*WW] * vb[gr*WW + gc];
        }
    }
    out[o] = acc;
}

extern "C" void kernel_launch(void* const* d_in, const int* in_sizes, int n_in,
                              void* d_out, int out_size, void* d_ws, size_t ws_size,
                              hipStream_t stream) {
    const float* x    = (const float*)d_in[0];
    const float* wq   = (const float*)d_in[1];
    const float* wk   = (const float*)d_in[2];
    const float* wv   = (const float*)d_in[3];
    const float* bias = (const float*)d_in[4];
    const float* relx = (const float*)d_in[5];
    const float* rely = (const float*)d_in[6];
    float* ws  = (float*)d_ws;
    float* out = (float*)d_out;

    proj_kernel<<<dim3(72, 6), dim3(256), 0, stream>>>(x, wq, wk, wv, ws);
    attn_scores_kernel<<<dim3(192), dim3(256), 0, stream>>>(relx, rely, ws);
    pv_kernel<<<dim3(9216), dim3(256), 0, stream>>>(bias, ws, out);
}

// Round 3
// 156.150 us; speedup vs baseline: 4.2177x; 1.9826x over previous
//
#include <hip/hip_runtime.h>

#define BB 4
#define CC 256
#define HH 48
#define WW 48
#define HWHW 2304
#define KK 49
#define RELN 128

// ws layout (floats): q | k | v | scores/attn
#define QSZ (BB*CC*HWHW)         // 2359296 floats per tensor
#define ATTNOFF (3*QSZ)          // scores: [B][H][64][W] (taps 0-48, qx 49-55, qy 56-62)
#define SBUF_FLOATS (BB*HH*64*WW)  // 589824

// ---------------- zero the score accumulator ----------------
__global__ __launch_bounds__(256) void zero_kernel(float* __restrict__ ws)
{
    float4* p = (float4*)(ws + ATTNOFF);
    int i = blockIdx.x*256 + threadIdx.x;
    p[i] = make_float4(0.f,0.f,0.f,0.f);   // 147456 float4 total
}

// ---------------- Projection GEMM ----------------
// D[768][9216] = Wcat[768][256] * X[256][9216]
__global__ __launch_bounds__(256) void proj_kernel(
    const float* __restrict__ x,
    const float* __restrict__ wq,
    const float* __restrict__ wk,
    const float* __restrict__ wvp,
    float* __restrict__ ws)
{
    __shared__ float Wt[32][132];
    __shared__ float Xs[32][128];

    const int m0 = blockIdx.y * 128;
    const int n0 = blockIdx.x * 128;
    const int b  = n0 / HWHW;
    const int hw0 = n0 % HWHW;

    const float* wsrc = (m0 < 256) ? wq : (m0 < 512) ? wk : wvp;
    const int mo = m0 & 255;

    const int tid = threadIdx.x;
    const int tn = tid & 15;
    const int tm = tid >> 4;

    float acc[2][2][4][4];
    #pragma unroll
    for (int p=0;p<2;p++)
      #pragma unroll
      for (int q=0;q<2;q++)
        #pragma unroll
        for (int i=0;i<4;i++)
          #pragma unroll
          for (int j=0;j<4;j++) acc[p][q][i][j]=0.f;

    const int wr = tid >> 1;
    const int wh = tid & 1;
    const int kkx = tid >> 3;
    const int cgx = tid & 7;

    for (int k0 = 0; k0 < 256; k0 += 32) {
        #pragma unroll
        for (int q4 = 0; q4 < 4; ++q4) {
            int koff = (wh*4 + q4) * 4;
            const float4 w4 = *(const float4*)(wsrc + (mo + wr)*256 + k0 + koff);
            Wt[koff+0][wr] = w4.x;
            Wt[koff+1][wr] = w4.y;
            Wt[koff+2][wr] = w4.z;
            Wt[koff+3][wr] = w4.w;
        }
        const float* xrow = x + (size_t)b*CC*HWHW + (size_t)(k0+kkx)*HWHW + hw0;
        #pragma unroll
        for (int j4 = 0; j4 < 4; ++j4) {
            int col = cgx*16 + j4*4;
            *(float4*)&Xs[kkx][col] = *(const float4*)(xrow + col);
        }
        __syncthreads();
        #pragma unroll
        for (int kk = 0; kk < 32; ++kk) {
            float4 a0 = *(const float4*)&Wt[kk][tm*4];
            float4 a1 = *(const float4*)&Wt[kk][64 + tm*4];
            float4 b0 = *(const float4*)&Xs[kk][tn*4];
            float4 b1 = *(const float4*)&Xs[kk][64 + tn*4];
            float av0[4] = {a0.x,a0.y,a0.z,a0.w};
            float av1[4] = {a1.x,a1.y,a1.z,a1.w};
            float bv0[4] = {b0.x,b0.y,b0.z,b0.w};
            float bv1[4] = {b1.x,b1.y,b1.z,b1.w};
            #pragma unroll
            for (int i=0;i<4;i++) {
                #pragma unroll
                for (int j=0;j<4;j++) {
                    acc[0][0][i][j] += av0[i]*bv0[j];
                    acc[0][1][i][j] += av0[i]*bv1[j];
                    acc[1][0][i][j] += av1[i]*bv0[j];
                    acc[1][1][i][j] += av1[i]*bv1[j];
                }
            }
        }
        __syncthreads();
    }
    #pragma unroll
    for (int p=0;p<2;p++) {
        #pragma unroll
        for (int i=0;i<4;i++) {
            int m = m0 + p*64 + tm*4 + i;
            int proj = m >> 8;
            int ch = m & 255;
            float* dst = ws + (size_t)proj*QSZ + (size_t)b*CC*HWHW + (size_t)ch*HWHW + hw0;
            #pragma unroll
            for (int q=0;q<2;q++) {
                int col = q*64 + tn*4;
                float4 o;
                o.x = acc[p][q][i][0]; o.y = acc[p][q][i][1];
                o.z = acc[p][q][i][2]; o.w = acc[p][q][i][3];
                *(float4*)(dst + col) = o;
            }
        }
    }
}

// ---------------- Scores partial ----------------
// block = (b, h, cg); cg selects 64 channels. 4 waves split TAPS (not channels):
// wave0: dk 0,1 | wave1: dk 2,3 | wave2: dk 4,5 | wave3: dk 6 + rel biases.
// Partials atomicAdd'ed into scores[B][H][64][W].
__global__ __launch_bounds__(256) void scores_partial_kernel(
    const float* __restrict__ relx,
    const float* __restrict__ rely,
    float* __restrict__ ws)
{
    const float* qbuf = ws;
    const float* kbuf = ws + QSZ;
    float* sbuf = ws + ATTNOFF;

    __shared__ float ks[16][7][56];   // 16 ch x 7 rows x cols(-3..50,+pad) = 25 KB

    const int bid = blockIdx.x;
    const int cg = bid & 3;           // channel group (64 ch)
    const int h  = (bid >> 2) % HH;
    const int b  = bid / (4*HH);

    const int tid = threadIdx.x;
    const int wv = tid >> 6;
    const int w = tid & 63;
    const bool act = (w < WW);

    float s[14];
    #pragma unroll
    for (int i=0;i<14;i++) s[i]=0.f;

    const float* rel = (cg < 2) ? relx : rely;
    const int relch0 = (cg < 2) ? 0 : RELN;

    for (int chunk = 0; chunk < 4; ++chunk) {
        const int c0 = cg*64 + chunk*16;
        // stage 16 ch x 7 rows x 54 cols (zero OOB)
        for (int t = 0; t < 25; ++t) {
            int fi = tid + t*256;
            if (fi < 6272) {
                int ci = fi / 392;
                int rem = fi - ci*392;
                int rw = rem / 56;
                int cl = rem - rw*56;
                int gr = h + rw - 3;
                int gc = cl - 3;
                float v = 0.f;
                if (cl < 54 && gr >= 0 && gr < HH && gc >= 0 && gc < WW)
                    v = kbuf[((size_t)b*CC + c0 + ci)*HWHW + gr*WW + gc];
                ks[ci][rw][cl] = v;
            }
        }
        __syncthreads();
        if (act) {
            #pragma unroll
            for (int ci = 0; ci < 16; ++ci) {
                const int ch = c0 + ci;
                const float qv = qbuf[((size_t)b*CC + ch)*HWHW + h*WW + w];
                if (wv < 3) {
                    const int dk0 = wv*2;
                    #pragma unroll
                    for (int dd = 0; dd < 2; ++dd) {
                        #pragma unroll
                        for (int dl = 0; dl < 7; ++dl)
                            s[dd*7+dl] += qv * ks[ci][dk0+dd][w + dl];
                    }
                } else {
                    #pragma unroll
                    for (int dl = 0; dl < 7; ++dl)
                        s[dl] += qv * ks[ci][6][w + dl];
                    const float* rp = rel + (ch - relch0)*7;
                    #pragma unroll
                    for (int l = 0; l < 7; ++l)
                        s[7+l] += qv * rp[l];
                }
            }
        }
        __syncthreads();
    }

    if (act) {
        float* base = sbuf + ((size_t)(b*HH + h)*64)*WW + w;
        if (wv < 3) {
            #pragma unroll
            for (int i = 0; i < 14; ++i)
                atomicAdd(base + (size_t)(wv*14 + i)*WW, s[i]);
        } else {
            #pragma unroll
            for (int i = 0; i < 7; ++i)
                atomicAdd(base + (size_t)(42 + i)*WW, s[i]);
            const int slot0 = (cg < 2) ? 49 : 56;
            #pragma unroll
            for (int l = 0; l < 7; ++l)
                atomicAdd(base + (size_t)(slot0 + l)*WW, s[7+l]);
        }
    }
}

// ---------------- Softmax finalize (in place) ----------------
// thread = (b,h,w). Reads 63 slots, softmax over 49 taps with rel biases, writes taps back.
__global__ __launch_bounds__(256) void softmax_kernel(float* __restrict__ ws)
{
    float* sbuf = ws + ATTNOFF;
    const int p = blockIdx.x*256 + threadIdx.x;   // 9216 pixels
    const int w = p % WW;
    const int h = (p / WW) % HH;
    const int b = p / (WW*HH);
    float* base = sbuf + ((size_t)(b*HH + h)*64)*WW + w;

    float tot[KK], qx[7], qy[7];
    #pragma unroll
    for (int i=0;i<KK;i++) tot[i] = base[(size_t)i*WW];
    #pragma unroll
    for (int l=0;l<7;l++) { qx[l] = base[(size_t)(49+l)*WW]; qy[l] = base[(size_t)(56+l)*WW]; }

    float mx = -1e30f;
    #pragma unroll
    for (int dk=0;dk<7;dk++) {
        #pragma unroll
        for (int dl=0;dl<7;dl++) {
            tot[dk*7+dl] += qy[dk] + qx[dl];
            mx = fmaxf(mx, tot[dk*7+dl]);
        }
    }
    float sum = 0.f;
    #pragma unroll
    for (int i=0;i<KK;i++) { float e = __expf(tot[i]-mx); tot[i]=e; sum += e; }
    float inv = 1.f/sum;
    #pragma unroll
    for (int i=0;i<KK;i++) base[(size_t)i*WW] = tot[i]*inv;
}

// ---------------- PV + bias ----------------
// block = (b, cg of 8 channels, pixel-tile of 256). attn in registers, 8 acc chains.
__global__ __launch_bounds__(256) void pv_kernel(
    const float* __restrict__ bias,
    const float* __restrict__ ws,
    float* __restrict__ out)
{
    const float* vbuf = ws + 2*QSZ;
    const float* attn = ws + ATTNOFF;

    const int bid = blockIdx.x;
    const int pt = bid % 9;
    const int cg = (bid / 9) % 32;
    const int b  = bid / (9*32);

    const int hw = pt*256 + threadIdx.x;
    const int w = hw % WW;
    const int h = hw / WW;

    const float* abase = attn + ((size_t)(b*HH + h)*64)*WW + w;
    float a[KK];
    #pragma unroll
    for (int i=0;i<KK;i++) a[i] = abase[(size_t)i*WW];

    const float* vbase = vbuf + ((size_t)b*CC + cg*8)*HWHW;
    float acc[8];
    #pragma unroll
    for (int ci=0;ci<8;ci++) acc[ci] = bias[cg*8+ci];

    #pragma unroll
    for (int dk=0;dk<7;dk++) {
        const int gr = h + dk - 3;
        if (gr < 0 || gr >= HH) continue;
        #pragma unroll
        for (int dl=0;dl<7;dl++) {
            const int gc = w + dl - 3;
            if (gc < 0 || gc >= WW) continue;
            const float av = a[dk*7+dl];
            const int off = gr*WW + gc;
            #pragma unroll
            for (int ci=0;ci<8;ci++)
                acc[ci] += av * vbase[(size_t)ci*HWHW + off];
        }
    }
    #pragma unroll
    for (int ci=0;ci<8;ci++)
        out[((size_t)b*CC + cg*8 + ci)*HWHW + hw] = acc[ci];
}

extern "C" void kernel_launch(void* const* d_in, const int* in_sizes, int n_in,
                              void* d_out, int out_size, void* d_ws, size_t ws_size,
                              hipStream_t stream) {
    const float* x    = (const float*)d_in[0];
    const float* wq   = (const float*)d_in[1];
    const float* wk   = (const float*)d_in[2];
    const float* wv   = (const float*)d_in[3];
    const float* bias = (const float*)d_in[4];
    const float* relx = (const float*)d_in[5];
    const float* rely = (const float*)d_in[6];
    float* ws  = (float*)d_ws;
    float* out = (float*)d_out;

    zero_kernel<<<dim3(SBUF_FLOATS/4/256), dim3(256), 0, stream>>>(ws);
    proj_kernel<<<dim3(72, 6), dim3(256), 0, stream>>>(x, wq, wk, wv, ws);
    scores_partial_kernel<<<dim3(BB*HH*4), dim3(256), 0, stream>>>(relx, rely, ws);
    softmax_kernel<<<dim3(36), dim3(256), 0, stream>>>(ws);
    pv_kernel<<<dim3(BB*32*9), dim3(256), 0, stream>>>(bias, ws, out);
}

// Round 4
// 125.856 us; speedup vs baseline: 5.2330x; 1.2407x over previous
//
#include <hip/hip_runtime.h>

#define BB 4
#define CC 256
#define HH 48
#define WW 48
#define HWHW 2304
#define KK 49
#define RELN 128

// ws layout (floats): q | k | v | scores/attn
// q,k,v are channel-packed: [b][c/4][h][w][4]
#define QSZ (BB*CC*HWHW)         // 2359296 floats per tensor
#define ATTNOFF (3*QSZ)          // scores: [B][H][64][W] (taps 0-48, qx 49-55, qy 56-62)
#define SBUF_FLOATS (BB*HH*64*WW)  // 589824

// ---------------- zero the score accumulator ----------------
__global__ __launch_bounds__(256) void zero_kernel(float* __restrict__ ws)
{
    float4* p = (float4*)(ws + ATTNOFF);
    int i = blockIdx.x*256 + threadIdx.x;
    p[i] = make_float4(0.f,0.f,0.f,0.f);
}

// ---------------- Projection GEMM ----------------
// D[768][9216] = Wcat[768][256] * X[256][9216], epilogue writes channel-packed.
__global__ __launch_bounds__(256) void proj_kernel(
    const float* __restrict__ x,
    const float* __restrict__ wq,
    const float* __restrict__ wk,
    const float* __restrict__ wvp,
    float* __restrict__ ws)
{
    __shared__ float Wt[32][132];
    __shared__ float Xs[32][128];

    const int m0 = blockIdx.y * 128;
    const int n0 = blockIdx.x * 128;
    const int b  = n0 / HWHW;
    const int hw0 = n0 % HWHW;

    const float* wsrc = (m0 < 256) ? wq : (m0 < 512) ? wk : wvp;
    const int mo = m0 & 255;

    const int tid = threadIdx.x;
    const int tn = tid & 15;
    const int tm = tid >> 4;

    float acc[2][2][4][4];
    #pragma unroll
    for (int p=0;p<2;p++)
      #pragma unroll
      for (int q=0;q<2;q++)
        #pragma unroll
        for (int i=0;i<4;i++)
          #pragma unroll
          for (int j=0;j<4;j++) acc[p][q][i][j]=0.f;

    const int wr = tid >> 1;
    const int wh = tid & 1;
    const int kkx = tid >> 3;
    const int cgx = tid & 7;

    for (int k0 = 0; k0 < 256; k0 += 32) {
        #pragma unroll
        for (int q4 = 0; q4 < 4; ++q4) {
            int koff = (wh*4 + q4) * 4;
            const float4 w4 = *(const float4*)(wsrc + (mo + wr)*256 + k0 + koff);
            Wt[koff+0][wr] = w4.x;
            Wt[koff+1][wr] = w4.y;
            Wt[koff+2][wr] = w4.z;
            Wt[koff+3][wr] = w4.w;
        }
        const float* xrow = x + (size_t)b*CC*HWHW + (size_t)(k0+kkx)*HWHW + hw0;
        #pragma unroll
        for (int j4 = 0; j4 < 4; ++j4) {
            int col = cgx*16 + j4*4;
            *(float4*)&Xs[kkx][col] = *(const float4*)(xrow + col);
        }
        __syncthreads();
        #pragma unroll
        for (int kk = 0; kk < 32; ++kk) {
            float4 a0 = *(const float4*)&Wt[kk][tm*4];
            float4 a1 = *(const float4*)&Wt[kk][64 + tm*4];
            float4 b0 = *(const float4*)&Xs[kk][tn*4];
            float4 b1 = *(const float4*)&Xs[kk][64 + tn*4];
            float av0[4] = {a0.x,a0.y,a0.z,a0.w};
            float av1[4] = {a1.x,a1.y,a1.z,a1.w};
            float bv0[4] = {b0.x,b0.y,b0.z,b0.w};
            float bv1[4] = {b1.x,b1.y,b1.z,b1.w};
            #pragma unroll
            for (int i=0;i<4;i++) {
                #pragma unroll
                for (int j=0;j<4;j++) {
                    acc[0][0][i][j] += av0[i]*bv0[j];
                    acc[0][1][i][j] += av0[i]*bv1[j];
                    acc[1][0][i][j] += av1[i]*bv0[j];
                    acc[1][1][i][j] += av1[i]*bv1[j];
                }
            }
        }
        __syncthreads();
    }
    // epilogue: channel-packed write. Thread holds 4 consecutive channels (i) x 4 pixels (j).
    #pragma unroll
    for (int p=0;p<2;p++) {
        #pragma unroll
        for (int q=0;q<2;q++) {
            const int mbase = m0 + p*64 + tm*4;
            const int proj = mbase >> 8;
            const int ch4 = (mbase & 255) >> 2;
            float* dst = ws + (size_t)proj*QSZ
                       + (((size_t)b*64 + ch4)*HWHW + hw0 + q*64 + tn*4)*4;
            #pragma unroll
            for (int j=0;j<4;j++) {
                float4 o;
                o.x = acc[p][q][0][j];
                o.y = acc[p][q][1][j];
                o.z = acc[p][q][2][j];
                o.w = acc[p][q][3][j];
                *(float4*)(dst + j*4) = o;
            }
        }
    }
}

// ---------------- Scores partial ----------------
// block = (b, h, cg); cg selects 64 channels. 4 waves split TAPS:
// wave0: dk 0,1 | wave1: dk 2,3 | wave2: dk 4,5 | wave3: dk 6 + rel biases.
// k staged in LDS channel-packed (ds_read_b128 feeds 4 FMAs).
__global__ __launch_bounds__(256) void scores_partial_kernel(
    const float* __restrict__ relx,
    const float* __restrict__ rely,
    float* __restrict__ ws)
{
    const float* qbuf = ws;
    const float* kbuf = ws + QSZ;
    float* sbuf = ws + ATTNOFF;

    __shared__ float ks[4][7][56][4];   // [ci4][row][col][ch] = 25088 B

    const int bid = blockIdx.x;
    const int cg = bid & 3;
    const int h  = (bid >> 2) % HH;
    const int b  = bid / (4*HH);

    const int tid = threadIdx.x;
    const int wv = tid >> 6;
    const int w = tid & 63;
    const bool act = (w < WW);

    float s[14];
    #pragma unroll
    for (int i=0;i<14;i++) s[i]=0.f;

    const float* rel = (cg < 2) ? relx : rely;
    const int relch0 = (cg < 2) ? 0 : RELN;

    for (int chunk = 0; chunk < 4; ++chunk) {
        const int cq0 = cg*16 + chunk*4;   // first packed channel-group
        // stage 4 groups x 7 rows x 54 cols of packed k (zero OOB)
        #pragma unroll
        for (int t = 0; t < 6; ++t) {
            int fi = tid + t*256;
            if (fi < 1512) {
                int ci4 = fi / 378;
                int rem = fi - ci4*378;
                int rw = rem / 54;
                int cl = rem - rw*54;
                int gr = h + rw - 3;
                int gc = cl - 3;
                float4 v = make_float4(0.f,0.f,0.f,0.f);
                if (gr >= 0 && gr < HH && gc >= 0 && gc < WW)
                    v = *(const float4*)(kbuf
                        + (((size_t)b*64 + cq0 + ci4)*HWHW + gr*WW + gc)*4);
                *(float4*)&ks[ci4][rw][cl][0] = v;
            }
        }
        __syncthreads();
        if (act) {
            #pragma unroll
            for (int ci4 = 0; ci4 < 4; ++ci4) {
                const float4 q4 = *(const float4*)(qbuf
                    + (((size_t)b*64 + cq0 + ci4)*HWHW + h*WW + w)*4);
                const float qa[4] = {q4.x, q4.y, q4.z, q4.w};
                if (wv < 3) {
                    #pragma unroll
                    for (int dd = 0; dd < 2; ++dd) {
                        const int row = wv*2 + dd;
                        #pragma unroll
                        for (int dl = 0; dl < 7; ++dl) {
                            const float4 kv = *(const float4*)&ks[ci4][row][w + dl][0];
                            s[dd*7+dl] += qa[0]*kv.x + qa[1]*kv.y + qa[2]*kv.z + qa[3]*kv.w;
                        }
                    }
                } else {
                    #pragma unroll
                    for (int dl = 0; dl < 7; ++dl) {
                        const float4 kv = *(const float4*)&ks[ci4][6][w + dl][0];
                        s[dl] += qa[0]*kv.x + qa[1]*kv.y + qa[2]*kv.z + qa[3]*kv.w;
                    }
                    #pragma unroll
                    for (int cc = 0; cc < 4; ++cc) {
                        const int ch = (cq0 + ci4)*4 + cc;
                        const float* rp = rel + (ch - relch0)*7;
                        #pragma unroll
                        for (int l = 0; l < 7; ++l)
                            s[7+l] += qa[cc] * rp[l];
                    }
                }
            }
        }
        __syncthreads();
    }

    if (act) {
        float* base = sbuf + ((size_t)(b*HH + h)*64)*WW + w;
        if (wv < 3) {
            #pragma unroll
            for (int i = 0; i < 14; ++i)
                atomicAdd(base + (size_t)(wv*14 + i)*WW, s[i]);
        } else {
            #pragma unroll
            for (int i = 0; i < 7; ++i)
                atomicAdd(base + (size_t)(42 + i)*WW, s[i]);
            const int slot0 = (cg < 2) ? 49 : 56;
            #pragma unroll
            for (int l = 0; l < 7; ++l)
                atomicAdd(base + (size_t)(slot0 + l)*WW, s[7+l]);
        }
    }
}

// ---------------- Softmax finalize (in place) ----------------
__global__ __launch_bounds__(256) void softmax_kernel(float* __restrict__ ws)
{
    float* sbuf = ws + ATTNOFF;
    const int p = blockIdx.x*256 + threadIdx.x;
    const int w = p % WW;
    const int h = (p / WW) % HH;
    const int b = p / (WW*HH);
    float* base = sbuf + ((size_t)(b*HH + h)*64)*WW + w;

    float tot[KK], qx[7], qy[7];
    #pragma unroll
    for (int i=0;i<KK;i++) tot[i] = base[(size_t)i*WW];
    #pragma unroll
    for (int l=0;l<7;l++) { qx[l] = base[(size_t)(49+l)*WW]; qy[l] = base[(size_t)(56+l)*WW]; }

    float mx = -1e30f;
    #pragma unroll
    for (int dk=0;dk<7;dk++) {
        #pragma unroll
        for (int dl=0;dl<7;dl++) {
            tot[dk*7+dl] += qy[dk] + qx[dl];
            mx = fmaxf(mx, tot[dk*7+dl]);
        }
    }
    float sum = 0.f;
    #pragma unroll
    for (int i=0;i<KK;i++) { float e = __expf(tot[i]-mx); tot[i]=e; sum += e; }
    float inv = 1.f/sum;
    #pragma unroll
    for (int i=0;i<KK;i++) base[(size_t)i*WW] = tot[i]*inv;
}

// ---------------- PV + bias ----------------
// block = (b, cg of 8 channels, pixel-tile of 256). attn in registers,
// v channel-packed: one dwordx4 load feeds 4 FMAs.
__global__ __launch_bounds__(256) void pv_kernel(
    const float* __restrict__ bias,
    const float* __restrict__ ws,
    float* __restrict__ out)
{
    const float* vbuf = ws + 2*QSZ;
    const float* attn = ws + ATTNOFF;

    const int bid = blockIdx.x;
    const int pt = bid % 9;
    const int cg = (bid / 9) % 32;
    const int b  = bid / (9*32);

    const int hw = pt*256 + threadIdx.x;
    const int w = hw % WW;
    const int h = hw / WW;

    const float* abase = attn + ((size_t)(b*HH + h)*64)*WW + w;
    float a[KK];
    #pragma unroll
    for (int i=0;i<KK;i++) a[i] = abase[(size_t)i*WW];

    const float* vb0 = vbuf + ((size_t)b*64 + cg*2)*HWHW*4;
    float acc[8];
    #pragma unroll
    for (int ci=0;ci<8;ci++) acc[ci] = bias[cg*8+ci];

    #pragma unroll
    for (int dk=0;dk<7;dk++) {
        const int gr = h + dk - 3;
        if (gr < 0 || gr >= HH) continue;
        #pragma unroll
        for (int dl=0;dl<7;dl++) {
            const int gc = w + dl - 3;
            if (gc < 0 || gc >= WW) continue;
            const float av = a[dk*7+dl];
            const size_t off = (size_t)(gr*WW + gc)*4;
            const float4 v0 = *(const float4*)(vb0 + off);
            const float4 v1 = *(const float4*)(vb0 + (size_t)HWHW*4 + off);
            acc[0] += av * v0.x; acc[1] += av * v0.y;
            acc[2] += av * v0.z; acc[3] += av * v0.w;
            acc[4] += av * v1.x; acc[5] += av * v1.y;
            acc[6] += av * v1.z; acc[7] += av * v1.w;
        }
    }
    #pragma unroll
    for (int ci=0;ci<8;ci++)
        out[((size_t)b*CC + cg*8 + ci)*HWHW + hw] = acc[ci];
}

extern "C" void kernel_launch(void* const* d_in, const int* in_sizes, int n_in,
                              void* d_out, int out_size, void* d_ws, size_t ws_size,
                              hipStream_t stream) {
    const float* x    = (const float*)d_in[0];
    const float* wq   = (const float*)d_in[1];
    const float* wk   = (const float*)d_in[2];
    const float* wv   = (const float*)d_in[3];
    const float* bias = (const float*)d_in[4];
    const float* relx = (const float*)d_in[5];
    const float* rely = (const float*)d_in[6];
    float* ws  = (float*)d_ws;
    float* out = (float*)d_out;

    zero_kernel<<<dim3(SBUF_FLOATS/4/256), dim3(256), 0, stream>>>(ws);
    proj_kernel<<<dim3(72, 6), dim3(256), 0, stream>>>(x, wq, wk, wv, ws);
    scores_partial_kernel<<<dim3(BB*HH*4), dim3(256), 0, stream>>>(relx, rely, ws);
    softmax_kernel<<<dim3(36), dim3(256), 0, stream>>>(ws);
    pv_kernel<<<dim3(BB*32*9), dim3(256), 0, stream>>>(bias, ws, out);
}

// Round 5
// 97.969 us; speedup vs baseline: 6.7225x; 1.2846x over previous
//
#include <hip/hip_runtime.h>

#define BB 4
#define CC 256
#define HH 48
#define WW 48
#define HWHW 2304
#define KK 49
#define RELN 128

// ws layout (floats): q | k | v | sbuf | WT
// q,k,v channel-packed: [b][c/4][h][w][4]
#define QSZ (BB*CC*HWHW)            // 2359296 floats per tensor
#define ATTNOFF (3*QSZ)             // sbuf: [B][H][64][W] (taps 0-48, qx 49-55, qy 56-62)
#define SBUF_FLOATS (BB*HH*64*WW)   // 589824
#define WTOFF (ATTNOFF + SBUF_FLOATS)  // WT: 768*512 u16 = 196608 floats
// XT (bf16 hi/lo of x, [9216][32kg][hi8|lo8] u16) lives in d_out (exactly out_size*4 bytes)

typedef short bf16x8 __attribute__((ext_vector_type(8)));
typedef float f32x4 __attribute__((ext_vector_type(4)));

__device__ __forceinline__ void split_bf16(float f, unsigned short& hi, unsigned short& lo)
{
    unsigned u = __float_as_uint(f);
    hi = (unsigned short)(u >> 16);                      // truncated bf16
    float r = f - __uint_as_float(u & 0xFFFF0000u);      // exact residual
    unsigned v = __float_as_uint(r);
    v += 0x7FFFu + ((v >> 16) & 1u);                     // RNE
    lo = (unsigned short)(v >> 16);
}

// ---------------- zero the score accumulator ----------------
__global__ __launch_bounds__(256) void zero_kernel(float* __restrict__ ws)
{
    float4* p = (float4*)(ws + ATTNOFF);
    int i = blockIdx.x*256 + threadIdx.x;
    p[i] = make_float4(0.f,0.f,0.f,0.f);
}

// ---------------- convert x -> XT (transposed, hi/lo chunked) ----------------
// XT row n = b*2304+hw: 32 kg-chunks x (8 hi u16 | 8 lo u16) = 512 u16 = 1KB.
// Block: one b, 32 hw rows, all 256 c. LDS transpose, swizzled chunks.
__global__ __launch_bounds__(256) void convert_x_kernel(
    const float* __restrict__ x, unsigned short* __restrict__ xt)
{
    __shared__ unsigned short lds[32*520];   // row stride 520 u16 (1040B, 16B-aligned)
    const int bid = blockIdx.x;              // 288 = 4b * 72
    const int b = bid / 72;
    const int hw0 = (bid % 72) * 32;
    const int t = threadIdx.x;
    const int hw = t & 31, cp = t >> 5;      // 32 hw x 8 c-phases
    #pragma unroll 4
    for (int i = 0; i < 32; ++i) {
        int c = i*8 + cp;
        float f = x[((size_t)b*CC + c)*HWHW + hw0 + hw];
        unsigned short hi, lo; split_bf16(f, hi, lo);
        int ch = i*2;                        // hi chunk; lo chunk = ch+1
        lds[hw*520 + ((ch       ^ (hw&7))*8) + cp] = hi;
        lds[hw*520 + (((ch + 1) ^ (hw&7))*8) + cp] = lo;
    }
    __syncthreads();
    const int hw2 = t >> 3, u = t & 7;
    uint4* xt4 = (uint4*)xt;
    const size_t rowbase = ((size_t)b*HWHW + hw0 + hw2) * 64;   // uint4 units
    #pragma unroll
    for (int j = 0; j < 8; ++j) {
        int chunk = j*8 + u;
        int swz = chunk ^ (hw2 & 7);
        uint4 v = *(const uint4*)&lds[hw2*520 + swz*8];
        xt4[rowbase + chunk] = v;
    }
}

// ---------------- convert weights -> WT ----------------
// WT row m (0..767 = q|k|v channels): 32 kg x (8 hi | 8 lo) u16 = 1KB.
__global__ __launch_bounds__(256) void convert_w_kernel(
    const float* __restrict__ wq, const float* __restrict__ wk,
    const float* __restrict__ wvp, unsigned short* __restrict__ wt)
{
    const int t = blockIdx.x*256 + threadIdx.x;   // 0..24575
    const int m = t >> 5, kg = t & 31;
    const float* src = (m < 256) ? wq : (m < 512) ? wk : wvp;
    const float* row = src + (size_t)(m & 255)*256 + kg*8;
    unsigned short h[8], l[8];
    #pragma unroll
    for (int j = 0; j < 8; ++j) split_bf16(row[j], h[j], l[j]);
    uint4 hv, lv;
    hv.x = (unsigned)h[0] | ((unsigned)h[1]<<16); hv.y = (unsigned)h[2] | ((unsigned)h[3]<<16);
    hv.z = (unsigned)h[4] | ((unsigned)h[5]<<16); hv.w = (unsigned)h[6] | ((unsigned)h[7]<<16);
    lv.x = (unsigned)l[0] | ((unsigned)l[1]<<16); lv.y = (unsigned)l[2] | ((unsigned)l[3]<<16);
    lv.z = (unsigned)l[4] | ((unsigned)l[5]<<16); lv.w = (unsigned)l[6] | ((unsigned)l[7]<<16);
    uint4* dst = (uint4*)(wt + (size_t)m*512 + kg*16);
    dst[0] = hv; dst[1] = lv;
}

// ---------------- Projection GEMM via split-bf16 MFMA ----------------
// C[768][9216] = W[768][256] x X[256][9216]; 3 passes hi*hi + hi*lo + lo*hi.
// BM=BN=128, KSTEP=32, 4 waves 2x2 (64x64 per wave), 16x16x32 bf16 MFMA.
__global__ __launch_bounds__(256) void proj_gemm_kernel(
    const unsigned short* __restrict__ xt,
    const unsigned short* __restrict__ wt,
    float* __restrict__ ws)
{
    __shared__ unsigned short Asm[128*64];   // 128 rows x 8 chunks x 8 u16, swizzled
    __shared__ unsigned short Bsm[128*64];
    const int n0 = blockIdx.x * 128;
    const int m0 = blockIdx.y * 128;
    const int b = n0 / HWHW;                 // 2304 % 128 == 0: no straddle
    const int hwb = n0 % HWHW;
    const int tid = threadIdx.x;
    const int wid = tid >> 6, ln = tid & 63;
    const int wm = wid >> 1, wn = wid & 1;
    const int l15 = ln & 15, g = ln >> 4;

    f32x4 acc[4][4];
    #pragma unroll
    for (int i = 0; i < 4; ++i)
        #pragma unroll
        for (int j = 0; j < 4; ++j) acc[i][j] = (f32x4){0.f,0.f,0.f,0.f};

    const uint4* wt4 = (const uint4*)wt;
    const uint4* xt4 = (const uint4*)xt;
    uint4* A4 = (uint4*)Asm;
    uint4* B4 = (uint4*)Bsm;

    for (int ks = 0; ks < 8; ++ks) {
        #pragma unroll
        for (int r = 0; r < 4; ++r) {
            int id = r*256 + tid;
            int row = id >> 3, s = id & 7;
            int slot = s ^ (row & 7);
            A4[row*8 + slot] = wt4[(size_t)(m0 + row)*64 + ks*8 + s];
            B4[row*8 + slot] = xt4[(size_t)(n0 + row)*64 + ks*8 + s];
        }
        __syncthreads();
        bf16x8 aH[4], aL[4], bH[4], bL[4];
        #pragma unroll
        for (int mt = 0; mt < 4; ++mt) {
            int rA = wm*64 + mt*16 + l15;
            aH[mt] = *(const bf16x8*)&Asm[rA*64 + (((2*g)   ^ (rA&7))*8)];
            aL[mt] = *(const bf16x8*)&Asm[rA*64 + (((2*g+1) ^ (rA&7))*8)];
        }
        #pragma unroll
        for (int nt = 0; nt < 4; ++nt) {
            int rB = wn*64 + nt*16 + l15;
            bH[nt] = *(const bf16x8*)&Bsm[rB*64 + (((2*g)   ^ (rB&7))*8)];
            bL[nt] = *(const bf16x8*)&Bsm[rB*64 + (((2*g+1) ^ (rB&7))*8)];
        }
        #pragma unroll
        for (int mt = 0; mt < 4; ++mt)
            #pragma unroll
            for (int nt = 0; nt < 4; ++nt) {
                acc[mt][nt] = __builtin_amdgcn_mfma_f32_16x16x32_bf16(aH[mt], bH[nt], acc[mt][nt], 0, 0, 0);
                acc[mt][nt] = __builtin_amdgcn_mfma_f32_16x16x32_bf16(aH[mt], bL[nt], acc[mt][nt], 0, 0, 0);
                acc[mt][nt] = __builtin_amdgcn_mfma_f32_16x16x32_bf16(aL[mt], bH[nt], acc[mt][nt], 0, 0, 0);
            }
        __syncthreads();
    }
    // epilogue: C/D layout col=lane&15, row=4*(lane>>4)+reg -> channel-packed float4
    const int proj = m0 >> 8;                 // BM=128 never straddles a projection
    #pragma unroll
    for (int mt = 0; mt < 4; ++mt) {
        int chb = (m0 & 255) + wm*64 + mt*16 + 4*g;   // 4-aligned channel base
        int ch4 = chb >> 2;
        #pragma unroll
        for (int nt = 0; nt < 4; ++nt) {
            int hw = hwb + wn*64 + nt*16 + l15;
            float* dst = ws + (size_t)proj*QSZ + (((size_t)b*64 + ch4)*HWHW + hw)*4;
            *(f32x4*)dst = acc[mt][nt];
        }
    }
}

// ---------------- Scores partial (unchanged) ----------------
__global__ __launch_bounds__(256) void scores_partial_kernel(
    const float* __restrict__ relx,
    const float* __restrict__ rely,
    float* __restrict__ ws)
{
    const float* qbuf = ws;
    const float* kbuf = ws + QSZ;
    float* sbuf = ws + ATTNOFF;

    __shared__ float ks[4][7][56][4];

    const int bid = blockIdx.x;
    const int cg = bid & 3;
    const int h  = (bid >> 2) % HH;
    const int b  = bid / (4*HH);

    const int tid = threadIdx.x;
    const int wv = tid >> 6;
    const int w = tid & 63;
    const bool act = (w < WW);

    float s[14];
    #pragma unroll
    for (int i=0;i<14;i++) s[i]=0.f;

    const float* rel = (cg < 2) ? relx : rely;
    const int relch0 = (cg < 2) ? 0 : RELN;

    for (int chunk = 0; chunk < 4; ++chunk) {
        const int cq0 = cg*16 + chunk*4;
        #pragma unroll
        for (int t = 0; t < 6; ++t) {
            int fi = tid + t*256;
            if (fi < 1512) {
                int ci4 = fi / 378;
                int rem = fi - ci4*378;
                int rw = rem / 54;
                int cl = rem - rw*54;
                int gr = h + rw - 3;
                int gc = cl - 3;
                float4 v = make_float4(0.f,0.f,0.f,0.f);
                if (gr >= 0 && gr < HH && gc >= 0 && gc < WW)
                    v = *(const float4*)(kbuf
                        + (((size_t)b*64 + cq0 + ci4)*HWHW + gr*WW + gc)*4);
                *(float4*)&ks[ci4][rw][cl][0] = v;
            }
        }
        __syncthreads();
        if (act) {
            #pragma unroll
            for (int ci4 = 0; ci4 < 4; ++ci4) {
                const float4 q4 = *(const float4*)(qbuf
                    + (((size_t)b*64 + cq0 + ci4)*HWHW + h*WW + w)*4);
                const float qa[4] = {q4.x, q4.y, q4.z, q4.w};
                if (wv < 3) {
                    #pragma unroll
                    for (int dd = 0; dd < 2; ++dd) {
                        const int row = wv*2 + dd;
                        #pragma unroll
                        for (int dl = 0; dl < 7; ++dl) {
                            const float4 kv = *(const float4*)&ks[ci4][row][w + dl][0];
                            s[dd*7+dl] += qa[0]*kv.x + qa[1]*kv.y + qa[2]*kv.z + qa[3]*kv.w;
                        }
                    }
                } else {
                    #pragma unroll
                    for (int dl = 0; dl < 7; ++dl) {
                        const float4 kv = *(const float4*)&ks[ci4][6][w + dl][0];
                        s[dl] += qa[0]*kv.x + qa[1]*kv.y + qa[2]*kv.z + qa[3]*kv.w;
                    }
                    #pragma unroll
                    for (int cc = 0; cc < 4; ++cc) {
                        const int ch = (cq0 + ci4)*4 + cc;
                        const float* rp = rel + (ch - relch0)*7;
                        #pragma unroll
                        for (int l = 0; l < 7; ++l)
                            s[7+l] += qa[cc] * rp[l];
                    }
                }
            }
        }
        __syncthreads();
    }

    if (act) {
        float* base = sbuf + ((size_t)(b*HH + h)*64)*WW + w;
        if (wv < 3) {
            #pragma unroll
            for (int i = 0; i < 14; ++i)
                atomicAdd(base + (size_t)(wv*14 + i)*WW, s[i]);
        } else {
            #pragma unroll
            for (int i = 0; i < 7; ++i)
                atomicAdd(base + (size_t)(42 + i)*WW, s[i]);
            const int slot0 = (cg < 2) ? 49 : 56;
            #pragma unroll
            for (int l = 0; l < 7; ++l)
                atomicAdd(base + (size_t)(slot0 + l)*WW, s[7+l]);
        }
    }
}

// ---------------- Softmax finalize (unchanged) ----------------
__global__ __launch_bounds__(256) void softmax_kernel(float* __restrict__ ws)
{
    float* sbuf = ws + ATTNOFF;
    const int p = blockIdx.x*256 + threadIdx.x;
    const int w = p % WW;
    const int h = (p / WW) % HH;
    const int b = p / (WW*HH);
    float* base = sbuf + ((size_t)(b*HH + h)*64)*WW + w;

    float tot[KK], qx[7], qy[7];
    #pragma unroll
    for (int i=0;i<KK;i++) tot[i] = base[(size_t)i*WW];
    #pragma unroll
    for (int l=0;l<7;l++) { qx[l] = base[(size_t)(49+l)*WW]; qy[l] = base[(size_t)(56+l)*WW]; }

    float mx = -1e30f;
    #pragma unroll
    for (int dk=0;dk<7;dk++) {
        #pragma unroll
        for (int dl=0;dl<7;dl++) {
            tot[dk*7+dl] += qy[dk] + qx[dl];
            mx = fmaxf(mx, tot[dk*7+dl]);
        }
    }
    float sum = 0.f;
    #pragma unroll
    for (int i=0;i<KK;i++) { float e = __expf(tot[i]-mx); tot[i]=e; sum += e; }
    float inv = 1.f/sum;
    #pragma unroll
    for (int i=0;i<KK;i++) base[(size_t)i*WW] = tot[i]*inv;
}

// ---------------- PV + bias (unchanged) ----------------
__global__ __launch_bounds__(256) void pv_kernel(
    const float* __restrict__ bias,
    const float* __restrict__ ws,
    float* __restrict__ out)
{
    const float* vbuf = ws + 2*QSZ;
    const float* attn = ws + ATTNOFF;

    const int bid = blockIdx.x;
    const int pt = bid % 9;
    const int cg = (bid / 9) % 32;
    const int b  = bid / (9*32);

    const int hw = pt*256 + threadIdx.x;
    const int w = hw % WW;
    const int h = hw / WW;

    const float* abase = attn + ((size_t)(b*HH + h)*64)*WW + w;
    float a[KK];
    #pragma unroll
    for (int i=0;i<KK;i++) a[i] = abase[(size_t)i*WW];

    const float* vb0 = vbuf + ((size_t)b*64 + cg*2)*HWHW*4;
    float acc[8];
    #pragma unroll
    for (int ci=0;ci<8;ci++) acc[ci] = bias[cg*8+ci];

    #pragma unroll
    for (int dk=0;dk<7;dk++) {
        const int gr = h + dk - 3;
        if (gr < 0 || gr >= HH) continue;
        #pragma unroll
        for (int dl=0;dl<7;dl++) {
            const int gc = w + dl - 3;
            if (gc < 0 || gc >= WW) continue;
            const float av = a[dk*7+dl];
            const size_t off = (size_t)(gr*WW + gc)*4;
            const float4 v0 = *(const float4*)(vb0 + off);
            const float4 v1 = *(const float4*)(vb0 + (size_t)HWHW*4 + off);
            acc[0] += av * v0.x; acc[1] += av * v0.y;
            acc[2] += av * v0.z; acc[3] += av * v0.w;
            acc[4] += av * v1.x; acc[5] += av * v1.y;
            acc[6] += av * v1.z; acc[7] += av * v1.w;
        }
    }
    #pragma unroll
    for (int ci=0;ci<8;ci++)
        out[((size_t)b*CC + cg*8 + ci)*HWHW + hw] = acc[ci];
}

extern "C" void kernel_launch(void* const* d_in, const int* in_sizes, int n_in,
                              void* d_out, int out_size, void* d_ws, size_t ws_size,
                              hipStream_t stream) {
    const float* x    = (const float*)d_in[0];
    const float* wq   = (const float*)d_in[1];
    const float* wk   = (const float*)d_in[2];
    const float* wv   = (const float*)d_in[3];
    const float* bias = (const float*)d_in[4];
    const float* relx = (const float*)d_in[5];
    const float* rely = (const float*)d_in[6];
    float* ws  = (float*)d_ws;
    float* out = (float*)d_out;
    unsigned short* xt = (unsigned short*)d_out;       // XT scratch: exactly out_size*4 bytes
    unsigned short* wt = (unsigned short*)(ws + WTOFF);

    zero_kernel<<<dim3(SBUF_FLOATS/4/256), dim3(256), 0, stream>>>(ws);
    convert_x_kernel<<<dim3(BB*72), dim3(256), 0, stream>>>(x, xt);
    convert_w_kernel<<<dim3(96), dim3(256), 0, stream>>>(wq, wk, wv, wt);
    proj_gemm_kernel<<<dim3(72, 6), dim3(256), 0, stream>>>(xt, wt, ws);
    scores_partial_kernel<<<dim3(BB*HH*4), dim3(256), 0, stream>>>(relx, rely, ws);
    softmax_kernel<<<dim3(36), dim3(256), 0, stream>>>(ws);
    pv_kernel<<<dim3(BB*32*9), dim3(256), 0, stream>>>(bias, ws, out);
}

// Round 6
// 85.912 us; speedup vs baseline: 7.6659x; 1.1403x over previous
//
#include <hip/hip_runtime.h>

#define BB 4
#define CC 256
#define HH 48
#define WW 48
#define HWHW 2304
#define KK 49
#define RELN 128

// ws layout (floats): q | k | v | sbuf | WT
// q,k,v channel-packed: [b][c/4][h][w][4]
#define QSZ (BB*CC*HWHW)            // 2359296 floats per tensor
#define ATTNOFF (3*QSZ)             // sbuf: [B][H][64][W] (taps 0-48, qx 49-55, qy 56-62)
#define SBUF_FLOATS (BB*HH*64*WW)   // 589824
#define WTOFF (ATTNOFF + SBUF_FLOATS)
// XT (bf16 hi/lo of x) lives in d_out

typedef short bf16x8 __attribute__((ext_vector_type(8)));
typedef float f32x4 __attribute__((ext_vector_type(4)));

__device__ __forceinline__ void split_bf16(float f, unsigned short& hi, unsigned short& lo)
{
    unsigned u = __float_as_uint(f);
    hi = (unsigned short)(u >> 16);
    float r = f - __uint_as_float(u & 0xFFFF0000u);
    unsigned v = __float_as_uint(r);
    v += 0x7FFFu + ((v >> 16) & 1u);
    lo = (unsigned short)(v >> 16);
}

// ---------------- prep: zero sbuf | convert x -> XT | convert w -> WT ----------------
__global__ __launch_bounds__(256) void prep_kernel(
    const float* __restrict__ x,
    const float* __restrict__ wq, const float* __restrict__ wk,
    const float* __restrict__ wvp,
    unsigned short* __restrict__ xt, unsigned short* __restrict__ wt,
    float* __restrict__ ws)
{
    __shared__ unsigned short lds[32*520];
    const int bid = blockIdx.x;
    const int t = threadIdx.x;

    if (bid < 576) {                       // zero sbuf (576*256 float4 = SBUF)
        float4* p = (float4*)(ws + ATTNOFF);
        p[bid*256 + t] = make_float4(0.f,0.f,0.f,0.f);
        return;
    }
    if (bid < 864) {                       // convert_x, 288 blocks
        const int bid2 = bid - 576;
        const int b = bid2 / 72;
        const int hw0 = (bid2 % 72) * 32;
        const int hw = t & 31, cp = t >> 5;
        #pragma unroll 4
        for (int i = 0; i < 32; ++i) {
            int c = i*8 + cp;
            float f = x[((size_t)b*CC + c)*HWHW + hw0 + hw];
            unsigned short hi, lo; split_bf16(f, hi, lo);
            int ch = i*2;
            lds[hw*520 + ((ch       ^ (hw&7))*8) + cp] = hi;
            lds[hw*520 + (((ch + 1) ^ (hw&7))*8) + cp] = lo;
        }
        __syncthreads();
        const int hw2 = t >> 3, u = t & 7;
        uint4* xt4 = (uint4*)xt;
        const size_t rowbase = ((size_t)b*HWHW + hw0 + hw2) * 64;
        #pragma unroll
        for (int j = 0; j < 8; ++j) {
            int chunk = j*8 + u;
            int swz = chunk ^ (hw2 & 7);
            uint4 v = *(const uint4*)&lds[hw2*520 + swz*8];
            xt4[rowbase + chunk] = v;
        }
        return;
    }
    {                                       // convert_w, 96 blocks
        const int tt = (bid - 864)*256 + t;
        const int m = tt >> 5, kg = tt & 31;
        const float* src = (m < 256) ? wq : (m < 512) ? wk : wvp;
        const float* row = src + (size_t)(m & 255)*256 + kg*8;
        unsigned short h[8], l[8];
        #pragma unroll
        for (int j = 0; j < 8; ++j) split_bf16(row[j], h[j], l[j]);
        uint4 hv, lv;
        hv.x = (unsigned)h[0] | ((unsigned)h[1]<<16); hv.y = (unsigned)h[2] | ((unsigned)h[3]<<16);
        hv.z = (unsigned)h[4] | ((unsigned)h[5]<<16); hv.w = (unsigned)h[6] | ((unsigned)h[7]<<16);
        lv.x = (unsigned)l[0] | ((unsigned)l[1]<<16); lv.y = (unsigned)l[2] | ((unsigned)l[3]<<16);
        lv.z = (unsigned)l[4] | ((unsigned)l[5]<<16); lv.w = (unsigned)l[6] | ((unsigned)l[7]<<16);
        uint4* dst = (uint4*)(wt + (size_t)m*512 + kg*16);
        dst[0] = hv; dst[1] = lv;
    }
}

// ---------------- Projection GEMM via split-bf16 MFMA (unchanged) ----------------
__global__ __launch_bounds__(256) void proj_gemm_kernel(
    const unsigned short* __restrict__ xt,
    const unsigned short* __restrict__ wt,
    float* __restrict__ ws)
{
    __shared__ unsigned short Asm[128*64];
    __shared__ unsigned short Bsm[128*64];
    const int n0 = blockIdx.x * 128;
    const int m0 = blockIdx.y * 128;
    const int b = n0 / HWHW;
    const int hwb = n0 % HWHW;
    const int tid = threadIdx.x;
    const int wid = tid >> 6, ln = tid & 63;
    const int wm = wid >> 1, wn = wid & 1;
    const int l15 = ln & 15, g = ln >> 4;

    f32x4 acc[4][4];
    #pragma unroll
    for (int i = 0; i < 4; ++i)
        #pragma unroll
        for (int j = 0; j < 4; ++j) acc[i][j] = (f32x4){0.f,0.f,0.f,0.f};

    const uint4* wt4 = (const uint4*)wt;
    const uint4* xt4 = (const uint4*)xt;
    uint4* A4 = (uint4*)Asm;
    uint4* B4 = (uint4*)Bsm;

    for (int ks = 0; ks < 8; ++ks) {
        #pragma unroll
        for (int r = 0; r < 4; ++r) {
            int id = r*256 + tid;
            int row = id >> 3, s = id & 7;
            int slot = s ^ (row & 7);
            A4[row*8 + slot] = wt4[(size_t)(m0 + row)*64 + ks*8 + s];
            B4[row*8 + slot] = xt4[(size_t)(n0 + row)*64 + ks*8 + s];
        }
        __syncthreads();
        bf16x8 aH[4], aL[4], bH[4], bL[4];
        #pragma unroll
        for (int mt = 0; mt < 4; ++mt) {
            int rA = wm*64 + mt*16 + l15;
            aH[mt] = *(const bf16x8*)&Asm[rA*64 + (((2*g)   ^ (rA&7))*8)];
            aL[mt] = *(const bf16x8*)&Asm[rA*64 + (((2*g+1) ^ (rA&7))*8)];
        }
        #pragma unroll
        for (int nt = 0; nt < 4; ++nt) {
            int rB = wn*64 + nt*16 + l15;
            bH[nt] = *(const bf16x8*)&Bsm[rB*64 + (((2*g)   ^ (rB&7))*8)];
            bL[nt] = *(const bf16x8*)&Bsm[rB*64 + (((2*g+1) ^ (rB&7))*8)];
        }
        #pragma unroll
        for (int mt = 0; mt < 4; ++mt)
            #pragma unroll
            for (int nt = 0; nt < 4; ++nt) {
                acc[mt][nt] = __builtin_amdgcn_mfma_f32_16x16x32_bf16(aH[mt], bH[nt], acc[mt][nt], 0, 0, 0);
                acc[mt][nt] = __builtin_amdgcn_mfma_f32_16x16x32_bf16(aH[mt], bL[nt], acc[mt][nt], 0, 0, 0);
                acc[mt][nt] = __builtin_amdgcn_mfma_f32_16x16x32_bf16(aL[mt], bH[nt], acc[mt][nt], 0, 0, 0);
            }
        __syncthreads();
    }
    const int proj = m0 >> 8;
    #pragma unroll
    for (int mt = 0; mt < 4; ++mt) {
        int chb = (m0 & 255) + wm*64 + mt*16 + 4*g;
        int ch4 = chb >> 2;
        #pragma unroll
        for (int nt = 0; nt < 4; ++nt) {
            int hw = hwb + wn*64 + nt*16 + l15;
            float* dst = ws + (size_t)proj*QSZ + (((size_t)b*64 + ch4)*HWHW + hw)*4;
            *(f32x4*)dst = acc[mt][nt];
        }
    }
}

// ---------------- Scores partial ----------------
// block = (b, h, cg8); cg8 selects 32 channels (8 packed groups). 1536 blocks.
// 4 waves split TAPS: wv0: dk0,1 | wv1: dk2,3 | wv2: dk4,5 | wv3: dk6 + rel.
__global__ __launch_bounds__(256) void scores_partial_kernel(
    const float* __restrict__ relx,
    const float* __restrict__ rely,
    float* __restrict__ ws)
{
    const float* qbuf = ws;
    const float* kbuf = ws + QSZ;
    float* sbuf = ws + ATTNOFF;

    __shared__ float ks[4][7][56][4];

    const int bid = blockIdx.x;
    const int cg8 = bid & 7;
    const int h  = (bid >> 3) % HH;
    const int b  = bid / (8*HH);

    const int tid = threadIdx.x;
    const int wv = tid >> 6;
    const int w = tid & 63;
    const bool act = (w < WW);

    float s[14];
    #pragma unroll
    for (int i=0;i<14;i++) s[i]=0.f;

    const float* rel = (cg8 < 4) ? relx : rely;
    const int relch0 = (cg8 < 4) ? 0 : RELN;

    for (int chunk = 0; chunk < 2; ++chunk) {
        const int cq0 = cg8*8 + chunk*4;
        #pragma unroll
        for (int t = 0; t < 6; ++t) {
            int fi = tid + t*256;
            if (fi < 1512) {
                int ci4 = fi / 378;
                int rem = fi - ci4*378;
                int rw = rem / 54;
                int cl = rem - rw*54;
                int gr = h + rw - 3;
                int gc = cl - 3;
                float4 v = make_float4(0.f,0.f,0.f,0.f);
                if (gr >= 0 && gr < HH && gc >= 0 && gc < WW)
                    v = *(const float4*)(kbuf
                        + (((size_t)b*64 + cq0 + ci4)*HWHW + gr*WW + gc)*4);
                *(float4*)&ks[ci4][rw][cl][0] = v;
            }
        }
        __syncthreads();
        if (act) {
            #pragma unroll
            for (int ci4 = 0; ci4 < 4; ++ci4) {
                const float4 q4 = *(const float4*)(qbuf
                    + (((size_t)b*64 + cq0 + ci4)*HWHW + h*WW + w)*4);
                const float qa[4] = {q4.x, q4.y, q4.z, q4.w};
                if (wv < 3) {
                    #pragma unroll
                    for (int dd = 0; dd < 2; ++dd) {
                        const int row = wv*2 + dd;
                        #pragma unroll
                        for (int dl = 0; dl < 7; ++dl) {
                            const float4 kv = *(const float4*)&ks[ci4][row][w + dl][0];
                            s[dd*7+dl] += qa[0]*kv.x + qa[1]*kv.y + qa[2]*kv.z + qa[3]*kv.w;
                        }
                    }
                } else {
                    #pragma unroll
                    for (int dl = 0; dl < 7; ++dl) {
                        const float4 kv = *(const float4*)&ks[ci4][6][w + dl][0];
                        s[dl] += qa[0]*kv.x + qa[1]*kv.y + qa[2]*kv.z + qa[3]*kv.w;
                    }
                    #pragma unroll
                    for (int cc = 0; cc < 4; ++cc) {
                        const int ch = (cq0 + ci4)*4 + cc;
                        const float* rp = rel + (ch - relch0)*7;
                        #pragma unroll
                        for (int l = 0; l < 7; ++l)
                            s[7+l] += qa[cc] * rp[l];
                    }
                }
            }
        }
        __syncthreads();
    }

    if (act) {
        float* base = sbuf + ((size_t)(b*HH + h)*64)*WW + w;
        if (wv < 3) {
            #pragma unroll
            for (int i = 0; i < 14; ++i)
                atomicAdd(base + (size_t)(wv*14 + i)*WW, s[i]);
        } else {
            #pragma unroll
            for (int i = 0; i < 7; ++i)
                atomicAdd(base + (size_t)(42 + i)*WW, s[i]);
            const int slot0 = (cg8 < 4) ? 49 : 56;
            #pragma unroll
            for (int l = 0; l < 7; ++l)
                atomicAdd(base + (size_t)(slot0 + l)*WW, s[7+l]);
        }
    }
}

// ---------------- Softmax finalize ----------------
__global__ __launch_bounds__(64) void softmax_kernel(float* __restrict__ ws)
{
    float* sbuf = ws + ATTNOFF;
    const int p = blockIdx.x*64 + threadIdx.x;
    const int w = p % WW;
    const int h = (p / WW) % HH;
    const int b = p / (WW*HH);
    float* base = sbuf + ((size_t)(b*HH + h)*64)*WW + w;

    float tot[KK], qx[7], qy[7];
    #pragma unroll
    for (int i=0;i<KK;i++) tot[i] = base[(size_t)i*WW];
    #pragma unroll
    for (int l=0;l<7;l++) { qx[l] = base[(size_t)(49+l)*WW]; qy[l] = base[(size_t)(56+l)*WW]; }

    float mx = -1e30f;
    #pragma unroll
    for (int dk=0;dk<7;dk++) {
        #pragma unroll
        for (int dl=0;dl<7;dl++) {
            tot[dk*7+dl] += qy[dk] + qx[dl];
            mx = fmaxf(mx, tot[dk*7+dl]);
        }
    }
    float sum = 0.f;
    #pragma unroll
    for (int i=0;i<KK;i++) { float e = __expf(tot[i]-mx); tot[i]=e; sum += e; }
    float inv = 1.f/sum;
    #pragma unroll
    for (int i=0;i<KK;i++) base[(size_t)i*WW] = tot[i]*inv;
}

// ---------------- PV + bias ----------------
// thread = 4 consecutive pixels x 4 channels (one packed group).
// Per k-row: 10-float4 register sliding window serves all 4 pixels' 7 taps.
// block = 128 threads: 32 pixel-groups x 4 packed groups. grid = 4b*16pgq*18pxt.
__global__ __launch_bounds__(128) void pv_kernel(
    const float* __restrict__ bias,
    const float* __restrict__ ws,
    float* __restrict__ out)
{
    const float* vbuf = ws + 2*QSZ;
    const float* attn = ws + ATTNOFF;

    const int bid = blockIdx.x;
    const int pxt = bid % 18;
    const int pgq = (bid / 18) % 16;
    const int b   = bid / (18*16);

    const int tid = threadIdx.x;
    const int pxg = tid & 31;
    const int pg  = pgq*4 + (tid >> 5);     // packed channel group 0..63

    const int hw0 = pxt*128 + pxg*4;        // 4 consecutive pixels, same row (48%4==0)
    const int w0 = hw0 % WW;
    const int h0 = hw0 / WW;

    const float* vb = vbuf + ((size_t)b*64 + pg)*HWHW*4;
    const float* ab = attn + ((size_t)(b*HH + h0)*64)*WW;

    const float4 b4 = *(const float4*)(bias + pg*4);
    f32x4 bias4 = (f32x4){b4.x, b4.y, b4.z, b4.w};
    f32x4 acc[4];
    #pragma unroll
    for (int p = 0; p < 4; ++p) acc[p] = bias4;

    #pragma unroll
    for (int dk = 0; dk < 7; ++dk) {
        const int gr = h0 + dk - 3;
        const bool rok = (gr >= 0 && gr < HH);
        f32x4 vrow[10];
        #pragma unroll
        for (int jj = 0; jj < 10; ++jj) {
            const int gc = w0 - 3 + jj;
            vrow[jj] = (rok && gc >= 0 && gc < WW)
                ? *(const f32x4*)(vb + ((size_t)gr*WW + gc)*4)
                : (f32x4){0.f,0.f,0.f,0.f};
        }
        const float* arow = ab + (size_t)(dk*7)*WW + w0;
        #pragma unroll
        for (int dl = 0; dl < 7; ++dl) {
            const float4 av = *(const float4*)(arow + (size_t)dl*WW);
            acc[0] += vrow[dl+0] * av.x;
            acc[1] += vrow[dl+1] * av.y;
            acc[2] += vrow[dl+2] * av.z;
            acc[3] += vrow[dl+3] * av.w;
        }
    }
    // transpose [px][ch] -> [ch][px] and store float4 along pixels
    #pragma unroll
    for (int c = 0; c < 4; ++c) {
        float4 o;
        o.x = acc[0][c]; o.y = acc[1][c]; o.z = acc[2][c]; o.w = acc[3][c];
        *(float4*)(out + ((size_t)b*CC + pg*4 + c)*HWHW + hw0) = o;
    }
}

extern "C" void kernel_launch(void* const* d_in, const int* in_sizes, int n_in,
                              void* d_out, int out_size, void* d_ws, size_t ws_size,
                              hipStream_t stream) {
    const float* x    = (const float*)d_in[0];
    const float* wq   = (const float*)d_in[1];
    const float* wk   = (const float*)d_in[2];
    const float* wv   = (const float*)d_in[3];
    const float* bias = (const float*)d_in[4];
    const float* relx = (const float*)d_in[5];
    const float* rely = (const float*)d_in[6];
    float* ws  = (float*)d_ws;
    float* out = (float*)d_out;
    unsigned short* xt = (unsigned short*)d_out;
    unsigned short* wt = (unsigned short*)(ws + WTOFF);

    prep_kernel<<<dim3(960), dim3(256), 0, stream>>>(x, wq, wk, wv, xt, wt, ws);
    proj_gemm_kernel<<<dim3(72, 6), dim3(256), 0, stream>>>(xt, wt, ws);
    scores_partial_kernel<<<dim3(BB*HH*8), dim3(256), 0, stream>>>(relx, rely, ws);
    softmax_kernel<<<dim3(144), dim3(64), 0, stream>>>(ws);
    pv_kernel<<<dim3(BB*16*18), dim3(128), 0, stream>>>(bias, ws, out);
}